// Round 9
// baseline (396.428 us; speedup 1.0000x reference)
//
#include <hip/hip_runtime.h>
#include <hip/hip_bf16.h>

#define B_ 8
#define C_ 128
#define H_ 128
#define W_ 128

typedef __bf16 bf16;
typedef __bf16 bf16x8 __attribute__((ext_vector_type(8)));
typedef __bf16 bf16x4 __attribute__((ext_vector_type(4)));
typedef float f32x4 __attribute__((ext_vector_type(4)));

#define GLD_LDS16(gsrc, ldsdst)                                                              \
    __builtin_amdgcn_global_load_lds((const __attribute__((address_space(1))) void*)(gsrc),  \
                                     (__attribute__((address_space(3))) void*)(ldsdst),      \
                                     16, 0, 0)

#define WAITVM0 asm volatile("s_waitcnt vmcnt(0)" ::: "memory")
#define WAITVM2 asm volatile("s_waitcnt vmcnt(2)" ::: "memory")
#define WAITVM4 asm volatile("s_waitcnt vmcnt(4)" ::: "memory")

__device__ __forceinline__ void barrier_raw() {
    __builtin_amdgcn_sched_barrier(0);
    __builtin_amdgcn_s_barrier();
    __builtin_amdgcn_sched_barrier(0);
}

// ---------------------------------------------------------------------------
// Weight prep: per-lane MFMA fragment order (lane i reads base + i*16B).
// Fragment for lane (l4=lane>>4, l15=lane&15): co = cg*16 + l15,
// cc = cb*32 + l4*8 + j.
// ---------------------------------------------------------------------------
__global__ void wprep1_kernel(const float* __restrict__ w, bf16* __restrict__ o) {
    // a_c1w [256co][128cc][9tap] -> [cb4][tap9][cg16][lane64][8] bf16
    int i = blockIdx.x * 256 + threadIdx.x;
    if (i >= 256 * 128 * 9) return;
    int tap = i % 9, cc = (i / 9) % 128, co = i / (9 * 128);
    int cb = cc >> 5, l4 = (cc >> 3) & 3, j = cc & 7;
    int cg = co >> 4, l15 = co & 15;
    o[((size_t)((cb * 9 + tap) * 16 + cg) * 64 + l4 * 16 + l15) * 8 + j] = (bf16)w[i];
}

__global__ void wprepE_kernel(const float* __restrict__ w, bf16* __restrict__ o) {
    // ew [3][128co][128cc][9] -> [e][cb4][tap9][cg8][lane64][8] bf16
    int i = blockIdx.x * 256 + threadIdx.x;
    if (i >= 3 * 128 * 128 * 9) return;
    int tap = i % 9, cc = (i / 9) % 128, co = (i / (9 * 128)) % 128, e = i / (9 * 128 * 128);
    int cb = cc >> 5, l4 = (cc >> 3) & 3, j = cc & 7;
    int cg = co >> 4, l15 = co & 15;
    o[((size_t)(((e * 4 + cb) * 9 + tap) * 8 + cg) * 64 + l4 * 16 + l15) * 8 + j] = (bf16)w[i];
}

__global__ void wprep3_kernel(const float* __restrict__ w, bf16* __restrict__ o) {
    // ew3 [3][128co][128cc] -> [e][ks4][cg8][lane64][8] bf16
    int i = blockIdx.x * 256 + threadIdx.x;
    if (i >= 3 * 128 * 128) return;
    int cc = i % 128, co = (i / 128) % 128, e = i / (128 * 128);
    int ks = cc >> 5, l4 = (cc >> 3) & 3, j = cc & 7;
    int cg = co >> 4, l15 = co & 15;
    o[((size_t)((e * 4 + ks) * 8 + cg) * 64 + l4 * 16 + l15) * 8 + j] = (bf16)w[i];
}

// ---------------------------------------------------------------------------
// |x| NCHW fp32 -> NHWC bf16
// ---------------------------------------------------------------------------
__global__ __launch_bounds__(256) void xpose_kernel(const float* __restrict__ x,
                                                    bf16* __restrict__ xa)
{
    const int cblk = blockIdx.x, h = blockIdx.y, b = blockIdx.z;
    const int t = threadIdx.x;
    __shared__ float sx[32][133];
    for (int i = t; i < 32 * 128; i += 256) {
        int c = i >> 7, w = i & 127;
        sx[c][w] = fabsf(x[((size_t)(b * C_ + cblk * 32 + c) * H_ + h) * W_ + w]);
    }
    __syncthreads();
    for (int g = t; g < 512; g += 256) {
        int w = g >> 2, slot = g & 3;
        bf16x8 v;
#pragma unroll
        for (int j = 0; j < 8; j++) v[j] = (bf16)sx[slot * 8 + j][w];
        *(bf16x8*)&xa[((size_t)(b * H_ + h) * W_ + w) * C_ + cblk * 32 + slot * 8] = v;
    }
}

// ---------------------------------------------------------------------------
// Staging tile: logical [3 halo rows][66 w][32 cc] bf16, granule
// g = row*264 + w*4 + sp, slot = sp ^ ((w>>1)&3). 792 real granules,
// buffer padded to 1024 (16384 B). Each thread issues exactly 2 loads.
// ---------------------------------------------------------------------------
__device__ __forceinline__ void stage3(const bf16* __restrict__ base,
    const bf16* __restrict__ zbuf, char* dst,
    int t, int b, int h, int w0, int cb)
{
#pragma unroll
    for (int k = 0; k < 2; k++) {
        int g = t + k * 512;
        char* d = dst + (size_t)((t & 448) + k * 512) * 16;
        const bf16* src = zbuf;
        int row = g / 264, rem = g - row * 264;
        int w = rem >> 2, sp = rem & 3;
        int slot = sp ^ ((w >> 1) & 3);
        int hh = h + row - 1, gw = w0 + w - 1;
        if (g < 792 && (unsigned)hh < 128u && (unsigned)gw < 128u)
            src = base + ((size_t)(b * H_ + hh) * W_ + gw) * C_ + cb * 32 + slot * 8;
        GLD_LDS16(src, d);
    }
}

// ---------------------------------------------------------------------------
// K1: conv3x3(|x|)+bias -> xh/kk + gating sums.
// Block = 1 row x 64 px x 256 co; wave = (co-quarter ww&3) x (px-half ww>>2),
// i.e. 32 px x 64 co. acc 32 regs; ds_reads 2/tap/wave.
// ---------------------------------------------------------------------------
__global__ __launch_bounds__(512, 4) void conv1_kernel(
    const bf16* __restrict__ xa, const bf16* __restrict__ wT1,
    const float* __restrict__ bias,
    bf16* __restrict__ xh, bf16* __restrict__ kk,
    float* __restrict__ meansum, const bf16* __restrict__ zbuf)
{
    const int bid = blockIdx.x;
    const int b = bid & 7, h = (bid >> 3) & 127, pxh = bid >> 10;
    const int w0 = pxh * 64;
    const int t = threadIdx.x, lane = t & 63, ww = t >> 6;
    const int l15 = lane & 15, l4 = lane >> 4;
    const int coq = ww & 3, pxhalf = ww >> 2;
    const int co0 = coq * 64;
    __shared__ char sm[32768];
    char* B0 = sm;
    char* B1 = sm + 16384;

    f32x4 acc[2][4];   // [nf px][mf co]
#pragma unroll
    for (int nf = 0; nf < 2; nf++)
#pragma unroll
        for (int mf = 0; mf < 4; mf++) acc[nf][mf] = (f32x4){0.f, 0.f, 0.f, 0.f};

    stage3(xa, zbuf, B0, t, b, h, w0, 0);
    stage3(xa, zbuf, B1, t, b, h, w0, 1);

#pragma unroll
    for (int cb = 0; cb < 4; cb++) {
        if (cb < 3) { WAITVM2; } else { WAITVM0; }
        barrier_raw();
        const char* buf = (cb & 1) ? B1 : B0;
#pragma unroll 1
        for (int dy = 0; dy < 3; dy++) {
#pragma unroll
            for (int dx = 0; dx < 3; dx++) {
                const int tap = dy * 3 + dx;
                int bofs[2];
#pragma unroll
                for (int nf = 0; nf < 2; nf++) {
                    int wl = pxhalf * 32 + nf * 16 + l15 + dx;
                    bofs[nf] = (dy * 264 + wl * 4 + (l4 ^ ((wl >> 1) & 3))) * 16;
                }
                bf16x8 iv[2];
#pragma unroll
                for (int nf = 0; nf < 2; nf++) iv[nf] = *(const bf16x8*)(buf + bofs[nf]);
                bf16x8 wf[4];
#pragma unroll
                for (int mf = 0; mf < 4; mf++)
                    wf[mf] = *(const bf16x8*)&wT1[(size_t)((cb * 9 + tap) * 16 + coq * 4 + mf) * 512 + lane * 8];
#pragma unroll
                for (int nf = 0; nf < 2; nf++)
#pragma unroll
                    for (int mf = 0; mf < 4; mf++)
                        acc[nf][mf] = __builtin_amdgcn_mfma_f32_16x16x32_bf16(wf[mf], iv[nf], acc[nf][mf], 0, 0, 0);
            }
        }
        if (cb < 2) {
            barrier_raw();
            stage3(xa, zbuf, (cb & 1) ? B1 : B0, t, b, h, w0, cb + 2);
        }
    }

    float bvv[4][4];
#pragma unroll
    for (int mf = 0; mf < 4; mf++)
#pragma unroll
        for (int r = 0; r < 4; r++) bvv[mf][r] = bias[co0 + mf * 16 + 4 * l4 + r];

    bf16* dst = (co0 < 128) ? xh : kk;
    const int cod = co0 & 127;
#pragma unroll
    for (int mf = 0; mf < 4; mf++) {
#pragma unroll
        for (int nf = 0; nf < 2; nf++) {
            int w = w0 + pxhalf * 32 + nf * 16 + l15;
            bf16x4 v;
#pragma unroll
            for (int r = 0; r < 4; r++) v[r] = (bf16)(acc[nf][mf][r] + bvv[mf][r]);
            *(bf16x4*)&dst[((size_t)(b * H_ + h) * W_ + w) * C_ + cod + mf * 16 + 4 * l4] = v;
        }
        if (co0 < 128) {
#pragma unroll
            for (int r = 0; r < 4; r++) {
                float s = 2.f * bvv[mf][r] + acc[0][mf][r] + acc[1][mf][r];
                s += __shfl_xor(s, 1, 64);
                s += __shfl_xor(s, 2, 64);
                s += __shfl_xor(s, 4, 64);
                s += __shfl_xor(s, 8, 64);
                if (l15 == 0)
                    atomicAdd(&meansum[b * 128 + co0 + mf * 16 + 4 * l4 + r], s);
            }
        }
    }
}

// ---------------------------------------------------------------------------
// K2: gating (top-2 of 3; drop argmin, ties drop larger index)
// ---------------------------------------------------------------------------
__global__ void gate_kernel(const float* __restrict__ meansum,
                            const float* __restrict__ gw,
                            float* __restrict__ gate)
{
    int b = threadIdx.x;
    if (b >= 8) return;
    float l[3];
    for (int e = 0; e < 3; e++) {
        float s = 0.f;
        for (int c = 0; c < 128; c++) s += meansum[b * 128 + c] * gw[e * 128 + c];
        l[e] = s * (1.0f / 16384.0f);
    }
    float m = fmaxf(l[0], fmaxf(l[1], l[2]));
    float p0 = expf(l[0] - m), p1 = expf(l[1] - m), p2 = expf(l[2] - m);
    float s = p0 + p1 + p2;
    float w[3] = { p0 / s, p1 / s, p2 / s };
    int dm = 0;
    if (w[1] <= w[0]) dm = 1;
    if (w[2] <= w[dm]) dm = 2;
    for (int e = 0; e < 3; e++) gate[b * 3 + e] = (e == dm) ? 0.f : w[e];
}

// ---------------------------------------------------------------------------
// K3a/K3b: fem_b(0) -> [C][9-region] map
// ---------------------------------------------------------------------------
__global__ __launch_bounds__(128) void out2a_kernel(
    const float* __restrict__ c1b,
    const float* __restrict__ ew1, const float* __restrict__ eb1,
    const float* __restrict__ ew2, const float* __restrict__ eb2,
    float* __restrict__ sprod)
{
    const int e = blockIdx.x >> 7, c = blockIdx.x & 127;
    const int t = threadIdx.x;
    float xv = c1b[t], kv = c1b[128 + t];
    const float* w1 = ew1 + ((size_t)(e * 128 + c) * 128 + t) * 9;
    const float* w2 = ew2 + ((size_t)(e * 128 + c) * 128 + t) * 9;
    __shared__ float rA[9][128], rB[9][128];
#pragma unroll
    for (int tp = 0; tp < 9; tp++) { rA[tp][t] = xv * w1[tp]; rB[tp][t] = kv * w2[tp]; }
    __syncthreads();
    for (int s = 64; s > 0; s >>= 1) {
        if (t < s)
#pragma unroll
            for (int tp = 0; tp < 9; tp++) { rA[tp][t] += rA[tp][t + s]; rB[tp][t] += rB[tp][t + s]; }
        __syncthreads();
    }
    if (t < 9) {
        int rcl = t / 3, ccl = t % 3;
        float av = eb1[e * 128 + c], bv = eb2[e * 128 + c];
#pragma unroll
        for (int i = 0; i < 3; i++)
#pragma unroll
            for (int j = 0; j < 3; j++) {
                bool iok = (rcl == 1) || (rcl == 0 && i >= 1) || (rcl == 2 && i <= 1);
                bool jok = (ccl == 1) || (ccl == 0 && j >= 1) || (ccl == 2 && j <= 1);
                if (iok && jok) { av += rA[i * 3 + j][0]; bv += rB[i * 3 + j][0]; }
            }
        sprod[(size_t)(e * 128 + c) * 9 + t] = av * bv;
    }
}

__global__ __launch_bounds__(128) void out2b_kernel(
    const float* __restrict__ c1b, const float* __restrict__ gw,
    const float* __restrict__ sprod, const float* __restrict__ ew3,
    const float* __restrict__ eb3, float* __restrict__ out2map)
{
    const int c = blockIdx.x;
    const int t = threadIdx.x;
    __shared__ float red[27][128];
#pragma unroll
    for (int e = 0; e < 3; e++) {
        float wv = ew3[(size_t)(e * 128 + c) * 128 + t];
#pragma unroll
        for (int r = 0; r < 9; r++) red[e * 9 + r][t] = wv * sprod[(size_t)(e * 128 + t) * 9 + r];
    }
    __syncthreads();
    for (int s = 64; s > 0; s >>= 1) {
        if (t < s)
#pragma unroll
            for (int q = 0; q < 27; q++) red[q][t] += red[q][t + s];
        __syncthreads();
    }
    __shared__ float lsh[3];
    if (t < 3) {
        float s = 0.f;
        for (int cc = 0; cc < 128; cc++) s += c1b[cc] * gw[t * 128 + cc];
        lsh[t] = s;
    }
    __syncthreads();
    if (t == 0) {
        float l0 = lsh[0], l1 = lsh[1], l2 = lsh[2];
        float m = fmaxf(l0, fmaxf(l1, l2));
        float p0 = expf(l0 - m), p1 = expf(l1 - m), p2 = expf(l2 - m);
        float ssum = p0 + p1 + p2;
        float wv[3] = { p0 / ssum, p1 / ssum, p2 / ssum };
        int dm = 0;
        if (wv[1] <= wv[0]) dm = 1;
        if (wv[2] <= wv[dm]) dm = 2;
        wv[dm] = 0.f;
        for (int r = 0; r < 9; r++) {
            float o = c1b[c];
            for (int e = 0; e < 3; e++)
                o += wv[e] * (red[e * 9 + r][0] + eb3[e * 128 + c]);
            out2map[c * 9 + r] = o;
        }
    }
}

// ---------------------------------------------------------------------------
// K4: wave = one (conv,expert) stream x px-half, 32 px x 128 co.
// ds_reads 2/tap/wave (4x fewer than R8). Tail pairs A/B via LDS bf16 tiles.
// ---------------------------------------------------------------------------
__global__ __launch_bounds__(512, 4) void expert_kernel(
    const bf16* __restrict__ xhp, const bf16* __restrict__ kkp,
    const bf16* __restrict__ we1, const float* __restrict__ eb1,
    const bf16* __restrict__ we2, const float* __restrict__ eb2,
    const bf16* __restrict__ w3, const float* __restrict__ eb3,
    const float* __restrict__ gate, const float* __restrict__ o2map,
    const float* __restrict__ x, float* __restrict__ out,
    const bf16* __restrict__ zbuf)
{
    const int bid = blockIdx.x;
    const int b = bid & 7, h = (bid >> 3) & 127, pxh = bid >> 10;
    const int w0 = pxh * 64;
    const int t = threadIdx.x, lane = t & 63, ww = t >> 6;
    const int l15 = lane & 15, l4 = lane >> 4;
    const int pe_w = ww & 1, conv_w = (ww >> 1) & 1, pxhalf = ww >> 2;
    __shared__ char sm[65536];
    char* X0 = sm;
    char* K0 = sm + 16384;
    char* X1 = sm + 32768;
    char* K1 = sm + 49152;

    float ga0 = gate[b * 3 + 0], ga1 = gate[b * 3 + 1], ga2 = gate[b * 3 + 2];
    int e0, e1; float w_e0, w_e1;
    if (ga0 > 0.f) { e0 = 0; w_e0 = ga0; if (ga1 > 0.f) { e1 = 1; w_e1 = ga1; } else { e1 = 2; w_e1 = ga2; } }
    else           { e0 = 1; w_e0 = ga1; e1 = 2; w_e1 = ga2; }

    const int ew = pe_w ? e1 : e0;
    const bf16* wsel = conv_w ? we2 : we1;

    f32x4 acc[2][8];   // [nf px][mf co]  (one (conv,expert) stream)
#pragma unroll
    for (int nf = 0; nf < 2; nf++)
#pragma unroll
        for (int mf = 0; mf < 8; mf++) acc[nf][mf] = (f32x4){0.f, 0.f, 0.f, 0.f};

    stage3(xhp, zbuf, X0, t, b, h, w0, 0);
    stage3(kkp, zbuf, K0, t, b, h, w0, 0);
    stage3(xhp, zbuf, X1, t, b, h, w0, 1);
    stage3(kkp, zbuf, K1, t, b, h, w0, 1);

#pragma unroll
    for (int cb = 0; cb < 4; cb++) {
        if (cb < 3) { WAITVM4; } else { WAITVM0; }
        barrier_raw();
        const char* X = (cb & 1) ? X1 : X0;
        const char* K = (cb & 1) ? K1 : K0;
        const char* IMG = conv_w ? K : X;

#pragma unroll 1
        for (int dy = 0; dy < 3; dy++) {
#pragma unroll
            for (int dx = 0; dx < 3; dx++) {
                const int tap = dy * 3 + dx;
                bf16x8 iv[2];
#pragma unroll
                for (int nf = 0; nf < 2; nf++) {
                    int wl = pxhalf * 32 + nf * 16 + l15 + dx;
                    iv[nf] = *(const bf16x8*)(IMG + (dy * 264 + wl * 4 + (l4 ^ ((wl >> 1) & 3))) * 16);
                }
#pragma unroll
                for (int half = 0; half < 2; half++) {
                    bf16x8 wf[4];
#pragma unroll
                    for (int m = 0; m < 4; m++)
                        wf[m] = *(const bf16x8*)&wsel[(size_t)(((ew * 4 + cb) * 9 + tap) * 8 + half * 4 + m) * 512 + lane * 8];
#pragma unroll
                    for (int nf = 0; nf < 2; nf++)
#pragma unroll
                        for (int m = 0; m < 4; m++)
                            acc[nf][half * 4 + m] = __builtin_amdgcn_mfma_f32_16x16x32_bf16(wf[m], iv[nf], acc[nf][half * 4 + m], 0, 0, 0);
                }
            }
        }

        if (cb < 2) {
            barrier_raw();
            stage3(xhp, zbuf, (cb & 1) ? X1 : X0, t, b, h, w0, cb + 2);
            stage3(kkp, zbuf, (cb & 1) ? K1 : K0, t, b, h, w0, cb + 2);
        }
    }
    // cb=3 read X1/K1; A/B exchange tiles use X0/K0 (last read at cb=2, whose
    // readers all passed cb=3's entry barrier) -> producer writes are safe.

    const int pxq = ww & 3, ch = ww >> 2;   // tail partition: 16 px x 64 co
    f32x4 oacc[4];
#pragma unroll
    for (int mf = 0; mf < 4; mf++) oacc[mf] = (f32x4){0.f, 0.f, 0.f, 0.f};

#pragma unroll
    for (int pe = 0; pe < 2; pe++) {
        const int epe = pe ? e1 : e0;
        const float wpe = pe ? w_e1 : w_e0;

        // producers: waves whose stream-expert matches pe write bias-added
        // conv result (bf16) into A tile (conv_a -> X0) / B tile (conv_b -> K0)
        if (pe_w == pe) {
            const float* bp = conv_w ? eb2 : eb1;
            char* T = conv_w ? K0 : X0;
#pragma unroll
            for (int mf = 0; mf < 8; mf++) {
                int cc = mf * 16 + 4 * l4;
                f32x4 bv4 = *(const f32x4*)&bp[epe * 128 + cc];
#pragma unroll
                for (int nf = 0; nf < 2; nf++) {
                    int px = pxhalf * 32 + nf * 16 + l15;
                    bf16x4 pv;
#pragma unroll
                    for (int r = 0; r < 4; r++) pv[r] = (bf16)(acc[nf][mf][r] + bv4[r]);
                    int byt = px * 256 + (((cc >> 3) ^ (px & 15)) * 16) + (cc & 7) * 2;
                    *(bf16x4*)(T + byt) = pv;
                }
            }
        }
        barrier_raw();

        // consumers: all 8 waves; P = A*B formed on the fly, 1x1 GEMM
        f32x4 eo[4];
#pragma unroll
        for (int mf = 0; mf < 4; mf++) eo[mf] = (f32x4){0.f, 0.f, 0.f, 0.f};
#pragma unroll 1
        for (int ks = 0; ks < 4; ks++) {
            bf16x8 a3[4];
#pragma unroll
            for (int mf = 0; mf < 4; mf++)
                a3[mf] = *(const bf16x8*)&w3[(size_t)((epe * 4 + ks) * 8 + ch * 4 + mf) * 512 + lane * 8];
            int px = pxq * 16 + l15;
            int byt = px * 256 + (((ks * 4 + l4) ^ (px & 15)) * 16);
            bf16x8 av = *(const bf16x8*)(X0 + byt);
            bf16x8 bv = *(const bf16x8*)(K0 + byt);
            bf16x8 pv;
#pragma unroll
            for (int j = 0; j < 8; j++) pv[j] = (bf16)((float)av[j] * (float)bv[j]);
#pragma unroll
            for (int mf = 0; mf < 4; mf++)
                eo[mf] = __builtin_amdgcn_mfma_f32_16x16x32_bf16(a3[mf], pv, eo[mf], 0, 0, 0);
        }
#pragma unroll
        for (int mf = 0; mf < 4; mf++) {
            f32x4 b3 = *(const f32x4*)&eb3[epe * 128 + ch * 64 + mf * 16 + 4 * l4];
#pragma unroll
            for (int r = 0; r < 4; r++) oacc[mf][r] += wpe * (eo[mf][r] + b3[r]);
        }
        barrier_raw();   // tiles reused by next expert
    }

    // ---- epilogue: single coalesced write ----
    const int rcl = (h == 0) ? 0 : ((h == 127) ? 2 : 1);
    const int px = pxq * 16 + l15;
    const int w = w0 + px;
    const int ccl = (w == 0) ? 0 : ((w == 127) ? 2 : 1);
#pragma unroll
    for (int mf = 0; mf < 4; mf++) {
        int cbase = ch * 64 + mf * 16 + 4 * l4;
        bf16x4 xv = *(const bf16x4*)&xhp[((size_t)(b * H_ + h) * W_ + w) * C_ + cbase];
#pragma unroll
        for (int r = 0; r < 4; r++) {
            size_t gi = ((size_t)(b * C_ + cbase + r) * H_ + h) * W_ + w;
            out[gi] = (float)xv[r] + x[gi] + o2map[(cbase + r) * 9 + rcl * 3 + ccl]
                    + oacc[mf][r];
        }
    }
}

// ---------------------------------------------------------------------------
extern "C" void kernel_launch(void* const* d_in, const int* in_sizes, int n_in,
                              void* d_out, int out_size, void* d_ws, size_t ws_size,
                              hipStream_t stream)
{
    const float* x      = (const float*)d_in[0];
    const float* a_c1w  = (const float*)d_in[1];
    const float* a_c1b  = (const float*)d_in[2];
    const float* a_gw   = (const float*)d_in[3];
    const float* a_ew1  = (const float*)d_in[4];
    const float* a_eb1  = (const float*)d_in[5];
    const float* a_ew2  = (const float*)d_in[6];
    const float* a_eb2  = (const float*)d_in[7];
    const float* a_ew3  = (const float*)d_in[8];
    const float* a_eb3  = (const float*)d_in[9];
    const float* b_c1b  = (const float*)d_in[11];
    const float* b_gw   = (const float*)d_in[12];
    const float* b_ew1  = (const float*)d_in[13];
    const float* b_eb1  = (const float*)d_in[14];
    const float* b_ew2  = (const float*)d_in[15];
    const float* b_eb2  = (const float*)d_in[16];
    const float* b_ew3  = (const float*)d_in[17];
    const float* b_eb3  = (const float*)d_in[18];
    float* out = (float*)d_out;

    char* ws = (char*)d_ws;
    bf16*  xh      = (bf16*)(ws);                      // 33554432 B
    bf16*  kk      = (bf16*)(ws + 33554432);           // 33554432 B
    bf16*  wT1     = (bf16*)(ws + 67108864);           // 589824 B
    bf16*  wTe1    = (bf16*)(ws + 67698688);           // 884736 B
    bf16*  wTe2    = (bf16*)(ws + 68583424);           // 884736 B
    bf16*  wT3     = (bf16*)(ws + 69468160);           // 98304 B
    float* meansum = (float*)(ws + 69566464);          // 4096 B
    float* gate    = (float*)(ws + 69570560);          // 128 B
    float* o2map   = (float*)(ws + 69570688);          // 4608 B
    bf16*  zbuf    = (bf16*)(ws + 69575296);           // 256 B
    float* sprod   = (float*)(ws + 69575552);          // 13824 B

    bf16* xa = (bf16*)d_out;   // |x| NHWC bf16 scratch (overwritten last)

    hipMemsetAsync(ws + 69566464, 0, 4096, stream);        // meansum
    hipMemsetAsync(ws + 69575296, 0, 256, stream);         // zero buffer

    wprep1_kernel<<<(256 * 128 * 9 + 255) / 256, 256, 0, stream>>>(a_c1w, wT1);
    wprepE_kernel<<<(3 * 128 * 128 * 9 + 255) / 256, 256, 0, stream>>>(a_ew1, wTe1);
    wprepE_kernel<<<(3 * 128 * 128 * 9 + 255) / 256, 256, 0, stream>>>(a_ew2, wTe2);
    wprep3_kernel<<<(3 * 128 * 128 + 255) / 256, 256, 0, stream>>>(a_ew3, wT3);

    xpose_kernel<<<dim3(4, 128, 8), 256, 0, stream>>>(x, xa);

    conv1_kernel<<<2048, 512, 0, stream>>>(xa, wT1, a_c1b, xh, kk, meansum, zbuf);

    gate_kernel<<<1, 64, 0, stream>>>(meansum, a_gw, gate);
    out2a_kernel<<<384, 128, 0, stream>>>(b_c1b, b_ew1, b_eb1, b_ew2, b_eb2, sprod);
    out2b_kernel<<<128, 128, 0, stream>>>(b_c1b, b_gw, sprod, b_ew3, b_eb3, o2map);

    expert_kernel<<<2048, 512, 0, stream>>>(
        xh, kk, wTe1, a_eb1, wTe2, a_eb2, wT3, a_eb3, gate, o2map, x, out, zbuf);
}

// Round 10
// 291.752 us; speedup vs baseline: 1.3588x; 1.3588x over previous
//
#include <hip/hip_runtime.h>
#include <hip/hip_bf16.h>

#define B_ 8
#define C_ 128
#define H_ 128
#define W_ 128

typedef __bf16 bf16;
typedef __bf16 bf16x8 __attribute__((ext_vector_type(8)));
typedef __bf16 bf16x4 __attribute__((ext_vector_type(4)));
typedef float f32x4 __attribute__((ext_vector_type(4)));

#define GLD_LDS16(gsrc, ldsdst)                                                              \
    __builtin_amdgcn_global_load_lds((const __attribute__((address_space(1))) void*)(gsrc),  \
                                     (__attribute__((address_space(3))) void*)(ldsdst),      \
                                     16, 0, 0)

#define WAITVM0 asm volatile("s_waitcnt vmcnt(0)" ::: "memory")
#define WAITLGKM0 asm volatile("s_waitcnt lgkmcnt(0)" ::: "memory")

__device__ __forceinline__ void barrier_raw() {
    __builtin_amdgcn_sched_barrier(0);
    __builtin_amdgcn_s_barrier();
    __builtin_amdgcn_sched_barrier(0);
}

// ---------------------------------------------------------------------------
// Merged weight prep: per-lane MFMA fragment order (lane i reads base+i*16B).
// Fragment for lane (l4=lane>>4, l15=lane&15): co = cg*16+l15, cc = cb*32+l4*8+j.
// ---------------------------------------------------------------------------
__global__ void wprep_all_kernel(const float* __restrict__ c1w,
                                 const float* __restrict__ ew1,
                                 const float* __restrict__ ew2,
                                 const float* __restrict__ ew3,
                                 bf16* __restrict__ o1, bf16* __restrict__ oe1,
                                 bf16* __restrict__ oe2, bf16* __restrict__ o3)
{
    int i = blockIdx.x * 256 + threadIdx.x;
    if (i < 294912) {
        // a_c1w [256co][128cc][9tap] -> [cb4][tap9][cg16][lane64][8]
        int tap = i % 9, cc = (i / 9) % 128, co = i / (9 * 128);
        int cb = cc >> 5, l4 = (cc >> 3) & 3, j = cc & 7;
        int cg = co >> 4, l15 = co & 15;
        o1[((size_t)((cb * 9 + tap) * 16 + cg) * 64 + l4 * 16 + l15) * 8 + j] = (bf16)c1w[i];
    } else if (i < 294912 + 2 * 442368) {
        int k = i - 294912;
        const float* src = (k < 442368) ? ew1 : ew2;
        bf16* dst = (k < 442368) ? oe1 : oe2;
        if (k >= 442368) k -= 442368;
        // ew [3][128co][128cc][9] -> [e][cb4][tap9][cg8][lane64][8]
        int tap = k % 9, cc = (k / 9) % 128, co = (k / (9 * 128)) % 128, e = k / (9 * 128 * 128);
        int cb = cc >> 5, l4 = (cc >> 3) & 3, j = cc & 7;
        int cg = co >> 4, l15 = co & 15;
        dst[((size_t)(((e * 4 + cb) * 9 + tap) * 8 + cg) * 64 + l4 * 16 + l15) * 8 + j] = (bf16)src[k];
    } else if (i < 294912 + 2 * 442368 + 49152) {
        int k = i - 294912 - 2 * 442368;
        // ew3 [3][128co][128cc] -> [e][ks4][cg8][lane64][8]
        int cc = k % 128, co = (k / 128) % 128, e = k / (128 * 128);
        int ks = cc >> 5, l4 = (cc >> 3) & 3, j = cc & 7;
        int cg = co >> 4, l15 = co & 15;
        o3[((size_t)((e * 4 + ks) * 8 + cg) * 64 + l4 * 16 + l15) * 8 + j] = (bf16)ew3[k];
    }
}

// ---------------------------------------------------------------------------
// |x| NCHW fp32 -> NHWC bf16
// ---------------------------------------------------------------------------
__global__ __launch_bounds__(256) void xpose_kernel(const float* __restrict__ x,
                                                    bf16* __restrict__ xa)
{
    const int cblk = blockIdx.x, h = blockIdx.y, b = blockIdx.z;
    const int t = threadIdx.x;
    __shared__ float sx[32][133];
    for (int i = t; i < 32 * 128; i += 256) {
        int c = i >> 7, w = i & 127;
        sx[c][w] = fabsf(x[((size_t)(b * C_ + cblk * 32 + c) * H_ + h) * W_ + w]);
    }
    __syncthreads();
    for (int g = t; g < 512; g += 256) {
        int w = g >> 2, slot = g & 3;
        bf16x8 v;
#pragma unroll
        for (int j = 0; j < 8; j++) v[j] = (bf16)sx[slot * 8 + j][w];
        *(bf16x8*)&xa[((size_t)(b * H_ + h) * W_ + w) * C_ + cblk * 32 + slot * 8] = v;
    }
}

// ---------------------------------------------------------------------------
// Staging tile: logical [3 halo rows][66 w][32 cc] bf16, granule
// g = row*264 + w*4 + sp, slot = sp ^ ((w>>1)&3). 792 real granules,
// buffer padded to 1024 (16384 B). Each thread issues exactly 2 loads.
// ---------------------------------------------------------------------------
__device__ __forceinline__ void stage3(const bf16* __restrict__ base,
    const bf16* __restrict__ zbuf, char* dst,
    int t, int b, int h, int w0, int cb)
{
#pragma unroll
    for (int k = 0; k < 2; k++) {
        int g = t + k * 512;
        char* d = dst + (size_t)((t & 448) + k * 512) * 16;
        const bf16* src = zbuf;
        int row = g / 264, rem = g - row * 264;
        int w = rem >> 2, sp = rem & 3;
        int slot = sp ^ ((w >> 1) & 3);
        int hh = h + row - 1, gw = w0 + w - 1;
        if (g < 792 && (unsigned)hh < 128u && (unsigned)gw < 128u)
            src = base + ((size_t)(b * H_ + hh) * W_ + gw) * C_ + cb * 32 + slot * 8;
        GLD_LDS16(src, d);
    }
}

// ---------------------------------------------------------------------------
// K1: conv3x3(|x|)+bias -> xh/kk + gating sums.
// Block = 1 row x 64 px x 256 co; wave = 64 px x 32 co (R8 partition).
// 1-ahead double buffer, 1 barrier/cb, mid-region stage, setprio on MFMA.
// ---------------------------------------------------------------------------
__global__ __launch_bounds__(512, 4) void conv1_kernel(
    const bf16* __restrict__ xa, const bf16* __restrict__ wT1,
    const float* __restrict__ bias,
    bf16* __restrict__ xh, bf16* __restrict__ kk,
    float* __restrict__ meansum, const bf16* __restrict__ zbuf)
{
    const int bid = blockIdx.x;
    const int b = bid & 7, h = (bid >> 3) & 127, pxh = bid >> 10;
    const int w0 = pxh * 64;
    const int t = threadIdx.x, lane = t & 63, ww = t >> 6;
    const int l15 = lane & 15, l4 = lane >> 4;
    const int co0 = ww * 32;
    __shared__ char sm[32768];
    char* B0 = sm;
    char* B1 = sm + 16384;

    f32x4 acc[2][4];   // [mf co][nf px]
#pragma unroll
    for (int mf = 0; mf < 2; mf++)
#pragma unroll
        for (int nf = 0; nf < 4; nf++) acc[mf][nf] = (f32x4){0.f, 0.f, 0.f, 0.f};

    stage3(xa, zbuf, B0, t, b, h, w0, 0);

    auto tapgrp = [&](const char* buf, int cb, int dy) {
#pragma unroll
        for (int dx = 0; dx < 3; dx++) {
            const int tap = dy * 3 + dx;
            bf16x8 af[2];
#pragma unroll
            for (int mf = 0; mf < 2; mf++)
                af[mf] = *(const bf16x8*)&wT1[(size_t)((cb * 9 + tap) * 16 + ww * 2 + mf) * 512 + lane * 8];
            bf16x8 bv[4];
#pragma unroll
            for (int nf = 0; nf < 4; nf++) {
                int wl = nf * 16 + l15 + dx;
                int byt = (dy * 264 + wl * 4 + (l4 ^ ((wl >> 1) & 3))) * 16;
                bv[nf] = *(const bf16x8*)(buf + byt);
            }
#pragma unroll
            for (int mf = 0; mf < 2; mf++)
#pragma unroll
                for (int nf = 0; nf < 4; nf++)
                    acc[mf][nf] = __builtin_amdgcn_mfma_f32_16x16x32_bf16(af[mf], bv[nf], acc[mf][nf], 0, 0, 0);
        }
    };

#pragma unroll
    for (int cb = 0; cb < 4; cb++) {
        WAITVM0;
        barrier_raw();
        const char* buf = (cb & 1) ? B1 : B0;
        __builtin_amdgcn_s_setprio(1);
        tapgrp(buf, cb, 0);
        __builtin_amdgcn_s_setprio(0);
        __builtin_amdgcn_sched_barrier(0);
        if (cb < 3) stage3(xa, zbuf, (cb & 1) ? B0 : B1, t, b, h, w0, cb + 1);
        __builtin_amdgcn_s_setprio(1);
        tapgrp(buf, cb, 1);
        tapgrp(buf, cb, 2);
        __builtin_amdgcn_s_setprio(0);
    }

    float bvv[2][4];
#pragma unroll
    for (int mf = 0; mf < 2; mf++)
#pragma unroll
        for (int r = 0; r < 4; r++) bvv[mf][r] = bias[co0 + mf * 16 + 4 * l4 + r];

    bf16* dst = (co0 < 128) ? xh : kk;
    const int cod = co0 & 127;
#pragma unroll
    for (int mf = 0; mf < 2; mf++) {
#pragma unroll
        for (int nf = 0; nf < 4; nf++) {
            int w = w0 + nf * 16 + l15;
            bf16x4 v;
#pragma unroll
            for (int r = 0; r < 4; r++) v[r] = (bf16)(acc[mf][nf][r] + bvv[mf][r]);
            *(bf16x4*)&dst[((size_t)(b * H_ + h) * W_ + w) * C_ + cod + mf * 16 + 4 * l4] = v;
        }
        if (co0 < 128) {
#pragma unroll
            for (int r = 0; r < 4; r++) {
                float s = 4.f * bvv[mf][r];
#pragma unroll
                for (int nf = 0; nf < 4; nf++) s += acc[mf][nf][r];
                s += __shfl_xor(s, 1, 64);
                s += __shfl_xor(s, 2, 64);
                s += __shfl_xor(s, 4, 64);
                s += __shfl_xor(s, 8, 64);
                if (l15 == 0)
                    atomicAdd(&meansum[b * 128 + co0 + mf * 16 + 4 * l4 + r], s);
            }
        }
    }
}

// ---------------------------------------------------------------------------
// K2: gating (top-2 of 3; drop argmin, ties drop larger index)
// ---------------------------------------------------------------------------
__global__ void gate_kernel(const float* __restrict__ meansum,
                            const float* __restrict__ gw,
                            float* __restrict__ gate)
{
    int b = threadIdx.x;
    if (b >= 8) return;
    float l[3];
    for (int e = 0; e < 3; e++) {
        float s = 0.f;
        for (int c = 0; c < 128; c++) s += meansum[b * 128 + c] * gw[e * 128 + c];
        l[e] = s * (1.0f / 16384.0f);
    }
    float m = fmaxf(l[0], fmaxf(l[1], l[2]));
    float p0 = expf(l[0] - m), p1 = expf(l[1] - m), p2 = expf(l[2] - m);
    float s = p0 + p1 + p2;
    float w[3] = { p0 / s, p1 / s, p2 / s };
    int dm = 0;
    if (w[1] <= w[0]) dm = 1;
    if (w[2] <= w[dm]) dm = 2;
    for (int e = 0; e < 3; e++) gate[b * 3 + e] = (e == dm) ? 0.f : w[e];
}

// ---------------------------------------------------------------------------
// K3a/K3b: fem_b(0) -> [C][9-region] map
// ---------------------------------------------------------------------------
__global__ __launch_bounds__(128) void out2a_kernel(
    const float* __restrict__ c1b,
    const float* __restrict__ ew1, const float* __restrict__ eb1,
    const float* __restrict__ ew2, const float* __restrict__ eb2,
    float* __restrict__ sprod)
{
    const int e = blockIdx.x >> 7, c = blockIdx.x & 127;
    const int t = threadIdx.x;
    float xv = c1b[t], kv = c1b[128 + t];
    const float* w1 = ew1 + ((size_t)(e * 128 + c) * 128 + t) * 9;
    const float* w2 = ew2 + ((size_t)(e * 128 + c) * 128 + t) * 9;
    __shared__ float rA[9][128], rB[9][128];
#pragma unroll
    for (int tp = 0; tp < 9; tp++) { rA[tp][t] = xv * w1[tp]; rB[tp][t] = kv * w2[tp]; }
    __syncthreads();
    for (int s = 64; s > 0; s >>= 1) {
        if (t < s)
#pragma unroll
            for (int tp = 0; tp < 9; tp++) { rA[tp][t] += rA[tp][t + s]; rB[tp][t] += rB[tp][t + s]; }
        __syncthreads();
    }
    if (t < 9) {
        int rcl = t / 3, ccl = t % 3;
        float av = eb1[e * 128 + c], bv = eb2[e * 128 + c];
#pragma unroll
        for (int i = 0; i < 3; i++)
#pragma unroll
            for (int j = 0; j < 3; j++) {
                bool iok = (rcl == 1) || (rcl == 0 && i >= 1) || (rcl == 2 && i <= 1);
                bool jok = (ccl == 1) || (ccl == 0 && j >= 1) || (ccl == 2 && j <= 1);
                if (iok && jok) { av += rA[i * 3 + j][0]; bv += rB[i * 3 + j][0]; }
            }
        sprod[(size_t)(e * 128 + c) * 9 + t] = av * bv;
    }
}

__global__ __launch_bounds__(128) void out2b_kernel(
    const float* __restrict__ c1b, const float* __restrict__ gw,
    const float* __restrict__ sprod, const float* __restrict__ ew3,
    const float* __restrict__ eb3, float* __restrict__ out2map)
{
    const int c = blockIdx.x;
    const int t = threadIdx.x;
    __shared__ float red[27][128];
#pragma unroll
    for (int e = 0; e < 3; e++) {
        float wv = ew3[(size_t)(e * 128 + c) * 128 + t];
#pragma unroll
        for (int r = 0; r < 9; r++) red[e * 9 + r][t] = wv * sprod[(size_t)(e * 128 + t) * 9 + r];
    }
    __syncthreads();
    for (int s = 64; s > 0; s >>= 1) {
        if (t < s)
#pragma unroll
            for (int q = 0; q < 27; q++) red[q][t] += red[q][t + s];
        __syncthreads();
    }
    __shared__ float lsh[3];
    if (t < 3) {
        float s = 0.f;
        for (int cc = 0; cc < 128; cc++) s += c1b[cc] * gw[t * 128 + cc];
        lsh[t] = s;
    }
    __syncthreads();
    if (t == 0) {
        float l0 = lsh[0], l1 = lsh[1], l2 = lsh[2];
        float m = fmaxf(l0, fmaxf(l1, l2));
        float p0 = expf(l0 - m), p1 = expf(l1 - m), p2 = expf(l2 - m);
        float ssum = p0 + p1 + p2;
        float wv[3] = { p0 / ssum, p1 / ssum, p2 / ssum };
        int dm = 0;
        if (wv[1] <= wv[0]) dm = 1;
        if (wv[2] <= wv[dm]) dm = 2;
        wv[dm] = 0.f;
        for (int r = 0; r < 9; r++) {
            float o = c1b[c];
            for (int e = 0; e < 3; e++)
                o += wv[e] * (red[e * 9 + r][0] + eb3[e * 128 + c]);
            out2map[c * 9 + r] = o;
        }
    }
}

// ---------------------------------------------------------------------------
// K4 (R8 partition): wave = 16 co x 64 px, both experts + both convs per wave.
// 1-ahead double buffer, 1 barrier/cb, mid-region stage, setprio on MFMA,
// tail: P_e0->X0, P_e1->K0, one barrier, both 1x1 GEMMs, single out write.
// ---------------------------------------------------------------------------
__global__ __launch_bounds__(512, 4) void expert_kernel(
    const bf16* __restrict__ xhp, const bf16* __restrict__ kkp,
    const bf16* __restrict__ we1, const float* __restrict__ eb1,
    const bf16* __restrict__ we2, const float* __restrict__ eb2,
    const bf16* __restrict__ w3, const float* __restrict__ eb3,
    const float* __restrict__ gate, const float* __restrict__ o2map,
    const float* __restrict__ x, float* __restrict__ out,
    const bf16* __restrict__ zbuf)
{
    const int bid = blockIdx.x;
    const int b = bid & 7, h = (bid >> 3) & 127, pxh = bid >> 10;
    const int w0 = pxh * 64;
    const int t = threadIdx.x, lane = t & 63, ww = t >> 6;
    const int l15 = lane & 15, l4 = lane >> 4;
    __shared__ char sm[65536];
    char* X0 = sm;
    char* K0 = sm + 16384;
    char* X1 = sm + 32768;
    char* K1 = sm + 49152;

    float ga0 = gate[b * 3 + 0], ga1 = gate[b * 3 + 1], ga2 = gate[b * 3 + 2];
    int e0, e1; float w_e0, w_e1;
    if (ga0 > 0.f) { e0 = 0; w_e0 = ga0; if (ga1 > 0.f) { e1 = 1; w_e1 = ga1; } else { e1 = 2; w_e1 = ga2; } }
    else           { e0 = 1; w_e0 = ga1; e1 = 2; w_e1 = ga2; }

    f32x4 aa[2][4], ab[2][4];   // [expert][nf]
#pragma unroll
    for (int pe = 0; pe < 2; pe++)
#pragma unroll
        for (int nf = 0; nf < 4; nf++) {
            aa[pe][nf] = (f32x4){0.f, 0.f, 0.f, 0.f};
            ab[pe][nf] = (f32x4){0.f, 0.f, 0.f, 0.f};
        }

    stage3(xhp, zbuf, X0, t, b, h, w0, 0);
    stage3(kkp, zbuf, K0, t, b, h, w0, 0);

    auto tapgrp = [&](const char* X, const char* K, int cb, int dy) {
#pragma unroll
        for (int dx = 0; dx < 3; dx++) {
            const int tap = dy * 3 + dx;
            int bofs[4];
#pragma unroll
            for (int nf = 0; nf < 4; nf++) {
                int wl = nf * 16 + l15 + dx;
                bofs[nf] = (dy * 264 + wl * 4 + (l4 ^ ((wl >> 1) & 3))) * 16;
            }
            bf16x8 a10 = *(const bf16x8*)&we1[(size_t)(((e0 * 4 + cb) * 9 + tap) * 8 + ww) * 512 + lane * 8];
            bf16x8 a11 = *(const bf16x8*)&we1[(size_t)(((e1 * 4 + cb) * 9 + tap) * 8 + ww) * 512 + lane * 8];
#pragma unroll
            for (int nf = 0; nf < 4; nf++) {
                bf16x8 bx = *(const bf16x8*)(X + bofs[nf]);
                aa[0][nf] = __builtin_amdgcn_mfma_f32_16x16x32_bf16(a10, bx, aa[0][nf], 0, 0, 0);
                aa[1][nf] = __builtin_amdgcn_mfma_f32_16x16x32_bf16(a11, bx, aa[1][nf], 0, 0, 0);
            }
            bf16x8 a20 = *(const bf16x8*)&we2[(size_t)(((e0 * 4 + cb) * 9 + tap) * 8 + ww) * 512 + lane * 8];
            bf16x8 a21 = *(const bf16x8*)&we2[(size_t)(((e1 * 4 + cb) * 9 + tap) * 8 + ww) * 512 + lane * 8];
#pragma unroll
            for (int nf = 0; nf < 4; nf++) {
                bf16x8 bk = *(const bf16x8*)(K + bofs[nf]);
                ab[0][nf] = __builtin_amdgcn_mfma_f32_16x16x32_bf16(a20, bk, ab[0][nf], 0, 0, 0);
                ab[1][nf] = __builtin_amdgcn_mfma_f32_16x16x32_bf16(a21, bk, ab[1][nf], 0, 0, 0);
            }
        }
    };

#pragma unroll
    for (int cb = 0; cb < 4; cb++) {
        WAITVM0;
        barrier_raw();
        const char* X = (cb & 1) ? X1 : X0;
        const char* K = (cb & 1) ? K1 : K0;
        __builtin_amdgcn_s_setprio(1);
        tapgrp(X, K, cb, 0);
        __builtin_amdgcn_s_setprio(0);
        __builtin_amdgcn_sched_barrier(0);
        if (cb < 3) {
            stage3(xhp, zbuf, (cb & 1) ? X0 : X1, t, b, h, w0, cb + 1);
            stage3(kkp, zbuf, (cb & 1) ? K0 : K1, t, b, h, w0, cb + 1);
        }
        __builtin_amdgcn_s_setprio(1);
        tapgrp(X, K, cb, 1);
        tapgrp(X, K, cb, 2);
        __builtin_amdgcn_s_setprio(0);
    }
    // Region 3 read X1/K1 (slot1); X0/K0 (slot0) last read at cb=2, and all
    // waves passed cb=3's entry barrier -> P writes to X0/K0 need no barrier.

    const int ccb = ww * 16 + 4 * l4;
#pragma unroll
    for (int pe = 0; pe < 2; pe++) {
        const int e = pe ? e1 : e0;
        char* T = pe ? K0 : X0;
        float b1v[4], b2v[4];
#pragma unroll
        for (int r = 0; r < 4; r++) {
            b1v[r] = eb1[e * 128 + ccb + r];
            b2v[r] = eb2[e * 128 + ccb + r];
        }
#pragma unroll
        for (int nf = 0; nf < 4; nf++) {
            int px = nf * 16 + l15;
            bf16x4 pv;
#pragma unroll
            for (int r = 0; r < 4; r++)
                pv[r] = (bf16)((aa[pe][nf][r] + b1v[r]) * (ab[pe][nf][r] + b2v[r]));
            int byt = px * 256 + (((ccb >> 3) ^ (px & 15)) * 16) + (ccb & 7) * 2;
            *(bf16x4*)(T + byt) = pv;
        }
    }
    WAITLGKM0;
    barrier_raw();

    // both 1x1 GEMMs back-to-back (P_e0 in X0, P_e1 in K0)
    f32x4 eoA[4], eoB[4];
#pragma unroll
    for (int nf = 0; nf < 4; nf++) {
        eoA[nf] = (f32x4){0.f, 0.f, 0.f, 0.f};
        eoB[nf] = (f32x4){0.f, 0.f, 0.f, 0.f};
    }
    __builtin_amdgcn_s_setprio(1);
#pragma unroll
    for (int ks = 0; ks < 4; ks++) {
        bf16x8 a3A = *(const bf16x8*)&w3[(size_t)((e0 * 4 + ks) * 8 + ww) * 512 + lane * 8];
        bf16x8 a3B = *(const bf16x8*)&w3[(size_t)((e1 * 4 + ks) * 8 + ww) * 512 + lane * 8];
#pragma unroll
        for (int nf = 0; nf < 4; nf++) {
            int px = nf * 16 + l15;
            int byt = px * 256 + (((ks * 4 + l4) ^ (px & 15)) * 16);
            bf16x8 bpA = *(const bf16x8*)(X0 + byt);
            bf16x8 bpB = *(const bf16x8*)(K0 + byt);
            eoA[nf] = __builtin_amdgcn_mfma_f32_16x16x32_bf16(a3A, bpA, eoA[nf], 0, 0, 0);
            eoB[nf] = __builtin_amdgcn_mfma_f32_16x16x32_bf16(a3B, bpB, eoB[nf], 0, 0, 0);
        }
    }
    __builtin_amdgcn_s_setprio(0);

    // ---- epilogue: single coalesced write ----
    const int rcl = (h == 0) ? 0 : ((h == 127) ? 2 : 1);
    float b30[4], b31[4];
#pragma unroll
    for (int r = 0; r < 4; r++) {
        b30[r] = eb3[e0 * 128 + ccb + r];
        b31[r] = eb3[e1 * 128 + ccb + r];
    }
#pragma unroll
    for (int nf = 0; nf < 4; nf++) {
        int w = w0 + nf * 16 + l15;
        bf16x4 xv = *(const bf16x4*)&xhp[((size_t)(b * H_ + h) * W_ + w) * C_ + ccb];
        int ccl = (w == 0) ? 0 : ((w == 127) ? 2 : 1);
#pragma unroll
        for (int r = 0; r < 4; r++) {
            size_t gi = ((size_t)(b * C_ + ccb + r) * H_ + h) * W_ + w;
            out[gi] = (float)xv[r] + x[gi] + o2map[(ccb + r) * 9 + rcl * 3 + ccl]
                    + w_e0 * (eoA[nf][r] + b30[r])
                    + w_e1 * (eoB[nf][r] + b31[r]);
        }
    }
}

// ---------------------------------------------------------------------------
extern "C" void kernel_launch(void* const* d_in, const int* in_sizes, int n_in,
                              void* d_out, int out_size, void* d_ws, size_t ws_size,
                              hipStream_t stream)
{
    const float* x      = (const float*)d_in[0];
    const float* a_c1w  = (const float*)d_in[1];
    const float* a_c1b  = (const float*)d_in[2];
    const float* a_gw   = (const float*)d_in[3];
    const float* a_ew1  = (const float*)d_in[4];
    const float* a_eb1  = (const float*)d_in[5];
    const float* a_ew2  = (const float*)d_in[6];
    const float* a_eb2  = (const float*)d_in[7];
    const float* a_ew3  = (const float*)d_in[8];
    const float* a_eb3  = (const float*)d_in[9];
    const float* b_c1b  = (const float*)d_in[11];
    const float* b_gw   = (const float*)d_in[12];
    const float* b_ew1  = (const float*)d_in[13];
    const float* b_eb1  = (const float*)d_in[14];
    const float* b_ew2  = (const float*)d_in[15];
    const float* b_eb2  = (const float*)d_in[16];
    const float* b_ew3  = (const float*)d_in[17];
    const float* b_eb3  = (const float*)d_in[18];
    float* out = (float*)d_out;

    char* ws = (char*)d_ws;
    bf16*  xh      = (bf16*)(ws);                      // 33554432 B
    bf16*  kk      = (bf16*)(ws + 33554432);           // 33554432 B
    bf16*  wT1     = (bf16*)(ws + 67108864);           // 589824 B
    bf16*  wTe1    = (bf16*)(ws + 67698688);           // 884736 B
    bf16*  wTe2    = (bf16*)(ws + 68583424);           // 884736 B
    bf16*  wT3     = (bf16*)(ws + 69468160);           // 98304 B
    float* meansum = (float*)(ws + 69566464);          // 4096 B
    float* gate    = (float*)(ws + 69570560);          // 128 B
    float* o2map   = (float*)(ws + 69570688);          // 4608 B
    bf16*  zbuf    = (bf16*)(ws + 69575296);           // 256 B
    float* sprod   = (float*)(ws + 69575552);          // 13824 B

    bf16* xa = (bf16*)d_out;   // |x| NHWC bf16 scratch (overwritten last)

    hipMemsetAsync(ws + 69566464, 0, 4096, stream);        // meansum
    hipMemsetAsync(ws + 69575296, 0, 256, stream);         // zero buffer

    wprep_all_kernel<<<4800, 256, 0, stream>>>(a_c1w, a_ew1, a_ew2, a_ew3,
                                               wT1, wTe1, wTe2, wT3);

    xpose_kernel<<<dim3(4, 128, 8), 256, 0, stream>>>(x, xa);

    conv1_kernel<<<2048, 512, 0, stream>>>(xa, wT1, a_c1b, xh, kk, meansum, zbuf);

    gate_kernel<<<1, 64, 0, stream>>>(meansum, a_gw, gate);
    out2a_kernel<<<384, 128, 0, stream>>>(b_c1b, b_ew1, b_eb1, b_ew2, b_eb2, sprod);
    out2b_kernel<<<128, 128, 0, stream>>>(b_c1b, b_gw, sprod, b_ew3, b_eb3, o2map);

    expert_kernel<<<2048, 512, 0, stream>>>(
        xh, kk, wTe1, a_eb1, wTe2, a_eb2, wT3, a_eb3, gate, o2map, x, out, zbuf);
}